// Round 1
// baseline (102.847 us; speedup 1.0000x reference)
//
#include <hip/hip_runtime.h>

// AdditiveAttention: B=2,H=8,Q=512,K=512,D=64
//   q_proj = query @ Wa_w.T + Wa_b          [B,H,Q,D]
//   k_proj = keys  @ Ua_w.T + Ua_b          [B,H,K,D]
//   scores = sum_d V_w[d]*tanh(q_proj+k_proj) + V_b   [B,H,Q,K]
//
// tanh(x) = 1 - 2/(1+e^{2x});  e^{2x} = exp2((qp+kp)*2*log2e)
// Phase 1 stores qc = qp*2log2e, kc = kp*2log2e into d_ws (4 MiB needed).
// Phase 2: score = (V_b + sum(V_w)) - 2 * sum_d V_w[d] * rcp(1+exp2(qc+kc))

#define BHX 16
#define SEQ 512
#define DDIM 64

__global__ __launch_bounds__(256) void proj_scale_kernel(
    const float* __restrict__ X,    // [R, 64] input rows
    const float* __restrict__ W,    // [64, 64]; out[e] = sum_d X[d]*W[e][d]
    const float* __restrict__ bias, // [64]
    float* __restrict__ out,        // [R, 64], pre-scaled by 2*log2(e)
    int R)
{
  __shared__ float Wl[64][65];  // +1 pad: lanes read W[d][e] with lane-varying d
  __shared__ float Xl[64][65];
  const int t    = threadIdx.x;
  const int lane = t & 63;
  const int wave = t >> 6;
  const int row0 = blockIdx.x * 64;

#pragma unroll
  for (int i = 0; i < 16; ++i) {
    int idx = i * 256 + t;
    Wl[idx >> 6][idx & 63] = W[idx];
    Xl[idx >> 6][idx & 63] = X[(size_t)row0 * 64 + idx];
  }
  __syncthreads();

  const float C = 2.885390081777926815f; // 2*log2(e)
  const int d = lane;
  const float b = bias[d];
  for (int i = 0; i < 16; ++i) {
    int r = wave + 4 * i;   // rows 0..63 of this block
    float acc = b;
#pragma unroll
    for (int e = 0; e < 64; ++e)
      acc = __builtin_fmaf(Xl[r][e], Wl[d][e], acc);
    out[(size_t)(row0 + r) * 64 + d] = acc * C;
  }
}

__global__ __launch_bounds__(256) void score_kernel(
    const float* __restrict__ qc,  // [BH, 512, 64] pre-scaled
    const float* __restrict__ kc,  // [BH, 512, 64] pre-scaled
    const float* __restrict__ Vw,  // [64]
    const float* __restrict__ Vb,  // [1]
    float* __restrict__ out)       // [BH, 512, 512]
{
  const int bh   = blockIdx.z;
  const int q0   = blockIdx.y * 64;
  const int k0   = blockIdx.x * 64;
  const int lane = threadIdx.x & 63;
  const int wave = threadIdx.x >> 6;

  // Each lane owns one k-row (64 floats) in registers -> zero LDS in hot loop.
  float kreg[64];
  const float4* kr4 =
      (const float4*)(kc + (size_t)(bh * SEQ + k0 + lane) * DDIM);
#pragma unroll
  for (int i = 0; i < 16; ++i) {
    float4 v = kr4[i];
    kreg[4 * i + 0] = v.x;
    kreg[4 * i + 1] = v.y;
    kreg[4 * i + 2] = v.z;
    kreg[4 * i + 3] = v.w;
  }

  // acc0 = V_b + sum_d V_w[d]  (wave-uniform, scalarized)
  float acc0 = Vb[0];
#pragma unroll
  for (int d = 0; d < 64; ++d) acc0 += Vw[d];

  for (int i = 0; i < 16; ++i) {
    int q = q0 + wave * 16 + i;
    // force wave-uniform base -> s_load of the q row through the scalar cache
    int qoff = __builtin_amdgcn_readfirstlane((bh * SEQ + q) * DDIM);
    const float* qrow = qc + qoff;
    float acc = 0.0f;
#pragma unroll
    for (int d = 0; d < 64; ++d) {
      float s = qrow[d] + kreg[d];              // VALU (sgpr + vgpr)
      float t = __builtin_amdgcn_exp2f(s);      // v_exp_f32
      float r = __builtin_amdgcn_rcpf(t + 1.0f);// v_rcp_f32
      acc = __builtin_fmaf(Vw[d], r, acc);      // v_fma_f32 (sgpr Vw)
    }
    out[(size_t)(bh * SEQ + q) * SEQ + k0 + lane] =
        __builtin_fmaf(-2.0f, acc, acc0);
  }
}

extern "C" void kernel_launch(void* const* d_in, const int* in_sizes, int n_in,
                              void* d_out, int out_size, void* d_ws, size_t ws_size,
                              hipStream_t stream) {
  const float* query = (const float*)d_in[0];  // [2,8,512,64]
  const float* keys  = (const float*)d_in[1];  // [2,8,512,64]
  const float* Wa_w  = (const float*)d_in[2];  // [64,64]
  const float* Wa_b  = (const float*)d_in[3];  // [64]
  const float* Ua_w  = (const float*)d_in[4];  // [64,64]
  const float* Ua_b  = (const float*)d_in[5];  // [64]
  const float* V_w   = (const float*)d_in[6];  // [64]
  const float* V_b   = (const float*)d_in[7];  // [1]
  float* out = (float*)d_out;

  const int R = BHX * SEQ;          // 8192 rows each
  float* qc = (float*)d_ws;         // 2 MiB
  float* kc = qc + (size_t)R * DDIM;// 2 MiB

  proj_scale_kernel<<<R / 64, 256, 0, stream>>>(query, Wa_w, Wa_b, qc, R);
  proj_scale_kernel<<<R / 64, 256, 0, stream>>>(keys,  Ua_w, Ua_b, kc, R);

  dim3 grid(SEQ / 64, SEQ / 64, BHX);  // (k-tiles, q-tiles, b*h)
  score_kernel<<<grid, 256, 0, stream>>>(qc, kc, V_w, V_b, out);
}

// Round 2
// 84.607 us; speedup vs baseline: 1.2156x; 1.2156x over previous
//
#include <hip/hip_runtime.h>

// AdditiveAttention: B=2,H=8,Q=512,K=512,D=64
//   scores[b,h,q,k] = V_b + sum_d V_w[d]*tanh(q_proj[q,d] + k_proj[k,d])
// tanh(x) = 1 - 2/(1+e^{2x});  e^{2x} = exp2((qp+kp)*2*log2e)
// Phase 1 stores qc = qp*2log2e, kc = kp*2log2e into d_ws.
// Phase 2: score = (V_b + sum(V_w)) - 2 * sum_d V_w[d] * rcp(1+exp2(qc+kc))

#define BHX 16
#define SEQ 512
#define DDIM 64

// One launch for BOTH projections. blocks 0..127: query@Wa, 128..255: keys@Ua.
// Design: lane d holds W row d (64 VGPRs); X rows are wave-uniform -> s_load;
// inner product is 64 v_fma with SGPR operand. No LDS.
__global__ __launch_bounds__(256)
__attribute__((amdgpu_waves_per_eu(2, 8)))
void proj_both_kernel(
    const float* __restrict__ query, const float* __restrict__ keys,
    const float* __restrict__ Wa_w,  const float* __restrict__ Wa_b,
    const float* __restrict__ Ua_w,  const float* __restrict__ Ua_b,
    float* __restrict__ qc, float* __restrict__ kc)
{
  const int t = threadIdx.x, lane = t & 63, wave = t >> 6;
  const bool is_k = blockIdx.x >= 128;
  const float* __restrict__ X  = is_k ? keys : query;
  const float* __restrict__ W  = is_k ? Ua_w : Wa_w;
  const float* __restrict__ Bv = is_k ? Ua_b : Wa_b;
  float* __restrict__ out      = is_k ? kc : qc;
  const int row0 = (blockIdx.x & 127) * 64;

  // W row for this lane's output dim, resident in VGPRs
  float w[64];
  const float4* W4 = (const float4*)(W + lane * DDIM);
#pragma unroll
  for (int i = 0; i < 16; ++i) {
    float4 v = W4[i];
    w[4*i] = v.x; w[4*i+1] = v.y; w[4*i+2] = v.z; w[4*i+3] = v.w;
  }
#pragma unroll
  for (int i = 0; i < 16; ++i)
    asm volatile("" : "+v"(w[4*i]), "+v"(w[4*i+1]), "+v"(w[4*i+2]), "+v"(w[4*i+3]));

  const float C  = 2.885390081777926815f;  // 2*log2(e)
  const float bC = Bv[lane] * C;

#pragma unroll 1
  for (int i = 0; i < 16; ++i) {          // 16 rows per wave
    const int r   = row0 + wave * 16 + i;
    const int off = __builtin_amdgcn_readfirstlane(r * DDIM);
    const float* xr = X + off;            // wave-uniform -> s_load
    float a0 = 0, a1 = 0, a2 = 0, a3 = 0;
#pragma unroll
    for (int e = 0; e < 64; e += 4) {
      a0 = __builtin_fmaf(xr[e],     w[e],     a0);
      a1 = __builtin_fmaf(xr[e + 1], w[e + 1], a1);
      a2 = __builtin_fmaf(xr[e + 2], w[e + 2], a2);
      a3 = __builtin_fmaf(xr[e + 3], w[e + 3], a3);
    }
    out[(size_t)r * DDIM + lane] = __builtin_fmaf((a0 + a1) + (a2 + a3), C, bC);
  }
}

__global__ __launch_bounds__(256)
__attribute__((amdgpu_waves_per_eu(3, 4)))
void score_kernel(
    const float* __restrict__ qc,  // [BH, 512, 64] pre-scaled
    const float* __restrict__ kc,  // [BH, 512, 64] pre-scaled
    const float* __restrict__ Vw,  // [64]
    const float* __restrict__ Vb,  // [1]
    float* __restrict__ out)       // [BH, 512, 512]
{
  const int bh   = blockIdx.z;
  const int q0   = blockIdx.y * 64;
  const int k0   = blockIdx.x * 64;
  const int lane = threadIdx.x & 63;
  const int wave = threadIdx.x >> 6;

  // Each lane owns one k-row (64 floats) in registers.
  float kreg[64];
  const float4* kr4 =
      (const float4*)(kc + (size_t)(bh * SEQ + k0 + lane) * DDIM);
#pragma unroll
  for (int i = 0; i < 16; ++i) {
    float4 v = kr4[i];
    kreg[4*i] = v.x; kreg[4*i+1] = v.y; kreg[4*i+2] = v.z; kreg[4*i+3] = v.w;
  }
  // Pin: asm redefines the values -> loads can no longer be rematerialized
  // into the hot loop (R1: VGPR=36 proved LLVM sank these loads).
#pragma unroll
  for (int i = 0; i < 16; ++i)
    asm volatile("" : "+v"(kreg[4*i]), "+v"(kreg[4*i+1]),
                      "+v"(kreg[4*i+2]), "+v"(kreg[4*i+3]));

  // acc0 = V_b + sum_d V_w[d]  (wave-uniform, scalar)
  float acc0 = Vb[0];
#pragma unroll
  for (int d = 0; d < 64; ++d) acc0 += Vw[d];

#pragma unroll 1
  for (int i = 0; i < 16; ++i) {
    const int q    = q0 + wave * 16 + i;
    const int qoff = __builtin_amdgcn_readfirstlane((bh * SEQ + q) * DDIM);
    const float* qrow = qc + qoff;        // wave-uniform -> s_load
    float acc = 0.0f;
#pragma unroll
    for (int d = 0; d < 64; ++d) {
      float s  = qrow[d] + kreg[d];                // v_add (sgpr + vgpr)
      float t2 = __builtin_amdgcn_exp2f(s);        // v_exp_f32
      float r  = __builtin_amdgcn_rcpf(t2 + 1.0f); // v_add + v_rcp_f32
      acc = __builtin_fmaf(Vw[d], r, acc);         // v_fma (sgpr Vw)
    }
    out[(size_t)(bh * SEQ + q) * SEQ + k0 + lane] =
        __builtin_fmaf(-2.0f, acc, acc0);
  }
}

extern "C" void kernel_launch(void* const* d_in, const int* in_sizes, int n_in,
                              void* d_out, int out_size, void* d_ws, size_t ws_size,
                              hipStream_t stream) {
  const float* query = (const float*)d_in[0];  // [2,8,512,64]
  const float* keys  = (const float*)d_in[1];  // [2,8,512,64]
  const float* Wa_w  = (const float*)d_in[2];  // [64,64]
  const float* Wa_b  = (const float*)d_in[3];  // [64]
  const float* Ua_w  = (const float*)d_in[4];  // [64,64]
  const float* Ua_b  = (const float*)d_in[5];  // [64]
  const float* V_w   = (const float*)d_in[6];  // [64]
  const float* V_b   = (const float*)d_in[7];  // [1]
  float* out = (float*)d_out;

  const int R = BHX * SEQ;                 // 8192 rows each
  float* qc = (float*)d_ws;                // 2 MiB
  float* kc = qc + (size_t)R * DDIM;       // 2 MiB

  proj_both_kernel<<<256, 256, 0, stream>>>(query, keys, Wa_w, Wa_b,
                                            Ua_w, Ua_b, qc, kc);

  dim3 grid(SEQ / 64, SEQ / 64, BHX);      // (k-tiles, q-tiles, b*h)
  score_kernel<<<grid, 256, 0, stream>>>(qc, kc, V_w, V_b, out);
}

// Round 3
// 48.704 us; speedup vs baseline: 2.1117x; 1.7371x over previous
//
#include <hip/hip_runtime.h>

// AdditiveAttention: B=2,H=8,Q=512,K=512,D=64
//   scores[b,h,q,k] = V_b + sum_d V_w[d]*tanh(q_proj[q,d] + k_proj[k,d])
//
// tanh(x) = 1 - 2/(1+e^{2x}),  e^{2(qp+kp)} = eq * (1/hk)
//   eq = exp2(C*qp), hk = exp2(-C*kp), C = 2*log2(e)
//   Vw/(1+e^{2x}) = Vw*hk/(hk+eq) = vhk/(hk+eq)
// score = (Vb + sum(Vw)) - 2 * sum_d vhk[d] / (hk[d] + eq[d])
// Pairwise rcp: v0/A + v1/B = (v0*B + v1*A) * rcp(A*B)  -> 1 trans per 2 elems.

#define BHX 16
#define SEQ 512
#define DDIM 64

// Both projections in one launch. blocks 0..511: query->eq, 512..1023: keys->hk.
// 16 rows/block, 4 rows/wave. Lane = output dim e; W row in VGPRs; X row via
// wave-uniform s_load.
__global__ __launch_bounds__(256) void proj_kernel(
    const float* __restrict__ query, const float* __restrict__ keys,
    const float* __restrict__ Wa_w,  const float* __restrict__ Wa_b,
    const float* __restrict__ Ua_w,  const float* __restrict__ Ua_b,
    float* __restrict__ eq, float* __restrict__ hk)
{
  const int t = threadIdx.x, lane = t & 63, wave = t >> 6;
  const bool is_k = blockIdx.x >= 512;
  const float* __restrict__ X  = is_k ? keys : query;
  const float* __restrict__ W  = is_k ? Ua_w : Wa_w;
  const float* __restrict__ Bv = is_k ? Ua_b : Wa_b;
  float* __restrict__ out      = is_k ? hk : eq;
  const int row0 = (blockIdx.x & 511) * 16;

  float w[64];
  const float4* W4 = (const float4*)(W + lane * DDIM);
#pragma unroll
  for (int i = 0; i < 16; ++i) {
    float4 v = W4[i];
    w[4*i] = v.x; w[4*i+1] = v.y; w[4*i+2] = v.z; w[4*i+3] = v.w;
  }
#pragma unroll
  for (int i = 0; i < 16; ++i)
    asm volatile("" : "+v"(w[4*i]), "+v"(w[4*i+1]), "+v"(w[4*i+2]), "+v"(w[4*i+3]));

  const float C = 2.885390081777926815f;          // 2*log2(e)
  const float b = Bv[lane];
  const float sgn = is_k ? -C : C;

#pragma unroll 1
  for (int i = 0; i < 4; ++i) {
    const int r   = row0 + wave * 4 + i;
    const int off = __builtin_amdgcn_readfirstlane(r * DDIM);
    const float* xr = X + off;                    // wave-uniform -> s_load
    float a0 = 0, a1 = 0, a2 = 0, a3 = 0;
#pragma unroll
    for (int e = 0; e < 64; e += 4) {
      a0 = __builtin_fmaf(xr[e],     w[e],     a0);
      a1 = __builtin_fmaf(xr[e + 1], w[e + 1], a1);
      a2 = __builtin_fmaf(xr[e + 2], w[e + 2], a2);
      a3 = __builtin_fmaf(xr[e + 3], w[e + 3], a3);
    }
    float p = ((a0 + a1) + (a2 + a3)) + b;
    out[(size_t)r * DDIM + lane] = __builtin_amdgcn_exp2f(sgn * p);
  }
}

__global__ __launch_bounds__(256) void score_kernel(
    const float* __restrict__ eq,   // [BH*512][64]
    const float* __restrict__ hk,   // [BH*512][64]
    const float* __restrict__ Vw,   // [64]
    const float* __restrict__ Vb,   // [1]
    float* __restrict__ out)        // [BH,512,512]
{
  // Transposed k-tile in LDS, +1 pad: read bank = (d+lane)%32 -> 2 lanes/bank
  // (free); staging write bank = (lane+k)%32 -> 2 lanes/bank (free).
  __shared__ float hk_l[64][65];
  __shared__ float vh_l[64][65];

  const int bh   = blockIdx.z;
  const int q0   = blockIdx.y * 64;
  const int k0   = blockIdx.x * 64;
  const int lane = threadIdx.x & 63;
  const int wave = threadIdx.x >> 6;

  const float vwl = Vw[lane];
  {
    // wave stages rows k = wave*16 .. wave*16+15; lane = d
    const float* base = hk + (size_t)(bh * SEQ + k0 + wave * 16) * DDIM;
#pragma unroll
    for (int r = 0; r < 16; ++r) {
      float h = base[r * DDIM + lane];
      hk_l[lane][wave * 16 + r] = h;
      vh_l[lane][wave * 16 + r] = vwl * h;
    }
  }

  // acc0 = V_b + sum_d V_w[d]   (uniform, once per thread)
  float acc0 = Vb[0];
#pragma unroll
  for (int d = 0; d < 64; ++d) acc0 += Vw[d];

  __syncthreads();

#pragma unroll 1
  for (int jp = 0; jp < 4; ++jp) {          // 4 q-quads per wave (16 q total)
    const int q    = q0 + wave * 16 + jp * 4;
    const int off  = __builtin_amdgcn_readfirstlane((bh * SEQ + q) * DDIM);
    const float* qr0 = eq + off;            // wave-uniform -> s_load
    const float* qr1 = qr0 + DDIM;
    const float* qr2 = qr1 + DDIM;
    const float* qr3 = qr2 + DDIM;
    float ac0 = 0.f, ac1 = 0.f, ac2 = 0.f, ac3 = 0.f;
#pragma unroll 1
    for (int c = 0; c < 4; ++c) {           // d-chunks of 16 (bounds SGPR live)
#pragma unroll
      for (int p = 0; p < 8; ++p) {         // d-pairs
        const int d = c * 16 + p * 2;
        const float h0 = hk_l[d][lane],     h1 = hk_l[d + 1][lane];
        const float v0 = vh_l[d][lane],     v1 = vh_l[d + 1][lane];
        {
          float A = h0 + qr0[d], B = h1 + qr0[d + 1];
          float num = __builtin_fmaf(v1, A, v0 * B);
          ac0 = __builtin_fmaf(num, __builtin_amdgcn_rcpf(A * B), ac0);
        }
        {
          float A = h0 + qr1[d], B = h1 + qr1[d + 1];
          float num = __builtin_fmaf(v1, A, v0 * B);
          ac1 = __builtin_fmaf(num, __builtin_amdgcn_rcpf(A * B), ac1);
        }
        {
          float A = h0 + qr2[d], B = h1 + qr2[d + 1];
          float num = __builtin_fmaf(v1, A, v0 * B);
          ac2 = __builtin_fmaf(num, __builtin_amdgcn_rcpf(A * B), ac2);
        }
        {
          float A = h0 + qr3[d], B = h1 + qr3[d + 1];
          float num = __builtin_fmaf(v1, A, v0 * B);
          ac3 = __builtin_fmaf(num, __builtin_amdgcn_rcpf(A * B), ac3);
        }
      }
    }
    const size_t ob = (size_t)(bh * SEQ + q) * SEQ + k0 + lane;
    out[ob]           = __builtin_fmaf(-2.f, ac0, acc0);
    out[ob + SEQ]     = __builtin_fmaf(-2.f, ac1, acc0);
    out[ob + 2 * SEQ] = __builtin_fmaf(-2.f, ac2, acc0);
    out[ob + 3 * SEQ] = __builtin_fmaf(-2.f, ac3, acc0);
  }
}

extern "C" void kernel_launch(void* const* d_in, const int* in_sizes, int n_in,
                              void* d_out, int out_size, void* d_ws, size_t ws_size,
                              hipStream_t stream) {
  const float* query = (const float*)d_in[0];  // [2,8,512,64]
  const float* keys  = (const float*)d_in[1];  // [2,8,512,64]
  const float* Wa_w  = (const float*)d_in[2];  // [64,64]
  const float* Wa_b  = (const float*)d_in[3];  // [64]
  const float* Ua_w  = (const float*)d_in[4];  // [64,64]
  const float* Ua_b  = (const float*)d_in[5];  // [64]
  const float* V_w   = (const float*)d_in[6];  // [64]
  const float* V_b   = (const float*)d_in[7];  // [1]
  float* out = (float*)d_out;

  const int R = BHX * SEQ;                 // 8192 rows each side
  float* eq = (float*)d_ws;                // 2 MiB
  float* hk = eq + (size_t)R * DDIM;       // 2 MiB

  proj_kernel<<<1024, 256, 0, stream>>>(query, keys, Wa_w, Wa_b,
                                        Ua_w, Ua_b, eq, hk);

  dim3 grid(SEQ / 64, SEQ / 64, BHX);      // (k-tiles, q-tiles, b*h)
  score_kernel<<<grid, 256, 0, stream>>>(eq, hk, V_w, V_b, out);
}